// Round 1
// 599.514 us; speedup vs baseline: 1.2487x; 1.2487x over previous
//
#include <hip/hip_runtime.h>

// N=50000, E=600000, IN_CH=128, EDGE_DIM=64, OUT_CH=128
// edge_index delivered as int32.
//
// R7: decouple the edge pipeline. The fused per-bucket kernel (kept below as
// fallback) was latency-starved: 6-deep serial dependent loop per wave,
// 12.5k waves total, ~11 cache lines in flight per CU. Replace with:
//   K8a msg_kernel  : 75k independent one-shot waves (tile x ch-half),
//                     gather u[src] + MFMA edge GEMM + leaky -> msgl (sorted)
//   K8b segsum_kernel: streaming per-bucket segment sum of msgl + sigmoid
// Falls back to the R6 fused kernel if ws_size < ~428 MB.

#define NB 3125
#define NB_SHIFT 4

typedef __bf16 bf16x8 __attribute__((ext_vector_type(8)));
typedef float  f32x4  __attribute__((ext_vector_type(4)));
typedef unsigned short ushort_t;
typedef unsigned int   uint_t;

__device__ __forceinline__ ushort_t f2b(float f) {   // RNE f32->bf16
    uint_t u = __float_as_uint(f);
    u += 0x7FFF + ((u >> 16) & 1);
    return (ushort_t)(u >> 16);
}
__device__ __forceinline__ uint_t pack2(float a, float b) {
    return (uint_t)f2b(a) | ((uint_t)f2b(b) << 16);
}

// ---------------------------------------------------------------------------
// K1: fold weights -> bf16 k-major tables + f32 bias.
// ---------------------------------------------------------------------------
__global__ void fuse_weights_kernel(const float* __restrict__ Wx,
                                    const float* __restrict__ bx,
                                    const float* __restrict__ We,
                                    const float* __restrict__ be,
                                    const float* __restrict__ Wm,
                                    const float* __restrict__ bm,
                                    ushort_t* __restrict__ WxmT16,
                                    ushort_t* __restrict__ WemT16,
                                    float* __restrict__ bf) {
    int idx = blockIdx.x * blockDim.x + threadIdx.x;
    if (idx < 128 * 128) {
        int r = idx >> 7, c = idx & 127;       // r=k, c=ch
        float acc = 0.f;
        #pragma unroll 8
        for (int j = 0; j < 128; ++j) acc += Wx[r * 128 + j] * Wm[j * 128 + c];
        WxmT16[c * 128 + r] = f2b(acc);
    } else if (idx < 128 * 128 + 64 * 128) {
        int t = idx - 128 * 128;
        int r = t >> 7, c = t & 127;           // r=k(<64), c=ch
        float acc = 0.f;
        #pragma unroll 8
        for (int j = 0; j < 128; ++j) acc += We[r * 128 + j] * Wm[(128 + j) * 128 + c];
        WemT16[c * 64 + r] = f2b(acc);
    } else if (idx < 128 * 128 + 64 * 128 + 128) {
        int c = idx - (128 * 128 + 64 * 128);
        float acc = bm[c];
        #pragma unroll 8
        for (int j = 0; j < 128; ++j)
            acc += bx[j] * Wm[j * 128 + c] + be[j] * Wm[(128 + j) * 128 + c];
        bf[c] = acc;
    }
}

// ---------------------------------------------------------------------------
// K2: stream-convert x to bf16.
// ---------------------------------------------------------------------------
__global__ void convert_x_kernel(const float* __restrict__ x,
                                 ushort_t* __restrict__ xb, int nx8) {
    int gid = blockIdx.x * blockDim.x + threadIdx.x;
    if (gid >= nx8) return;
    const float4* s = (const float4*)x + (size_t)gid * 2;
    float4 v0 = s[0], v1 = s[1];
    uint4 w;
    w.x = pack2(v0.x, v0.y);
    w.y = pack2(v0.z, v0.w);
    w.z = pack2(v1.x, v1.y);
    w.w = pack2(v1.z, v1.w);
    ((uint4*)xb)[gid] = w;
}

// ---------------------------------------------------------------------------
// K3: u = xb @ WxmT16 + bf  (bf16 MFMA, no LDS, no barriers).
// ---------------------------------------------------------------------------
__global__ __launch_bounds__(256) void node_gemm_kernel(
        const ushort_t* __restrict__ xb, const ushort_t* __restrict__ WxmT16,
        const float* __restrict__ bf, float* __restrict__ u, int N) {
    int tid = threadIdx.x;
    int g = blockIdx.x * 4 + (tid >> 6);
    if (g >= (N / 16) * 2) return;
    int lane = tid & 63, l15 = lane & 15, quad = lane >> 4;
    int n0 = (g >> 1) * 16;
    int chBase = (g & 1) * 64;

    bf16x8 B[4][4];
    #pragma unroll
    for (int ct = 0; ct < 4; ++ct)
        #pragma unroll
        for (int kk = 0; kk < 4; ++kk)
            B[ct][kk] = __builtin_bit_cast(bf16x8, *((const uint4*)
                &WxmT16[(size_t)(chBase + ct * 16 + l15) * 128 + kk * 32 + quad * 8]));

    bf16x8 A[4];
    #pragma unroll
    for (int kk = 0; kk < 4; ++kk)
        A[kk] = __builtin_bit_cast(bf16x8, *((const uint4*)
            &xb[(size_t)(n0 + l15) * 128 + kk * 32 + quad * 8]));

    f32x4 acc[4] = {{0.f,0.f,0.f,0.f},{0.f,0.f,0.f,0.f},
                    {0.f,0.f,0.f,0.f},{0.f,0.f,0.f,0.f}};
    #pragma unroll
    for (int kk = 0; kk < 4; ++kk)
        #pragma unroll
        for (int ct = 0; ct < 4; ++ct)
            acc[ct] = __builtin_amdgcn_mfma_f32_16x16x32_bf16(A[kk], B[ct][kk], acc[ct], 0, 0, 0);

    #pragma unroll
    for (int ct = 0; ct < 4; ++ct) {
        float bias = bf[chBase + ct * 16 + l15];
        #pragma unroll
        for (int r = 0; r < 4; ++r)
            u[(size_t)(n0 + quad * 4 + r) * 128 + chBase + ct * 16 + l15] = acc[ct][r] + bias;
    }
}

// ---------------------------------------------------------------------------
// K4: LDS-binned histogram of dst buckets.
// ---------------------------------------------------------------------------
__global__ __launch_bounds__(1024) void hist_kernel(
        const int* __restrict__ ei, int* __restrict__ cnt, int E) {
    __shared__ int lcnt[NB];
    int t = threadIdx.x;
    for (int i = t; i < NB; i += 1024) lcnt[i] = 0;
    __syncthreads();
    int base = blockIdx.x * 8192;
    #pragma unroll
    for (int j = 0; j < 8; ++j) {
        int e = base + t + j * 1024;
        if (e < E) atomicAdd(&lcnt[ei[E + e] >> NB_SHIFT], 1);
    }
    __syncthreads();
    for (int i = t; i < NB; i += 1024) {
        int c = lcnt[i];
        if (c) atomicAdd(&cnt[i], c);
    }
}

// ---------------------------------------------------------------------------
// K5: exclusive scan of cnt -> start, cur. Single block, 4 elems/thread.
// ---------------------------------------------------------------------------
__global__ __launch_bounds__(1024) void scan_kernel(
        const int* __restrict__ cnt, int* __restrict__ start,
        int* __restrict__ cur, int nb, int E) {
    __shared__ int tot[1024];
    int t = threadIdx.x;
    int v[4]; int sum = 0;
    #pragma unroll
    for (int j = 0; j < 4; ++j) {
        int i = t * 4 + j;
        v[j] = (i < nb) ? cnt[i] : 0;
        sum += v[j];
    }
    tot[t] = sum;
    __syncthreads();
    for (int d = 1; d < 1024; d <<= 1) {
        int val = tot[t];
        int add = (t >= d) ? tot[t - d] : 0;
        __syncthreads();
        tot[t] = val + add;
        __syncthreads();
    }
    int ex = (t == 0) ? 0 : tot[t - 1];
    #pragma unroll
    for (int j = 0; j < 4; ++j) {
        int i = t * 4 + j;
        if (i < nb) { start[i] = ex; cur[i] = ex; }
        ex += v[j];
    }
    if (t == 1023) start[nb] = ex;   // == E
}

// ---------------------------------------------------------------------------
// K6: block rank-and-reserve binning: pos[e], recs[pos] = src | dstl<<16.
// ---------------------------------------------------------------------------
__global__ __launch_bounds__(1024) void binpos_kernel(
        const int* __restrict__ ei, int* __restrict__ cur,
        int* __restrict__ pos, uint_t* __restrict__ recs, int E) {
    __shared__ int lcnt[NB];
    __shared__ int lbase[NB];
    int t = threadIdx.x;
    for (int i = t; i < NB; i += 1024) lcnt[i] = 0;
    __syncthreads();
    int base = blockIdx.x * 8192;
    int myrank[8], mybkt[8];
    #pragma unroll
    for (int j = 0; j < 8; ++j) {
        int e = base + t + j * 1024;
        if (e < E) {
            int b = ei[E + e] >> NB_SHIFT;
            mybkt[j] = b;
            myrank[j] = atomicAdd(&lcnt[b], 1);
        }
    }
    __syncthreads();
    for (int i = t; i < NB; i += 1024) {
        int c = lcnt[i];
        lbase[i] = c ? atomicAdd(&cur[i], c) : 0;
    }
    __syncthreads();
    #pragma unroll
    for (int j = 0; j < 8; ++j) {
        int e = base + t + j * 1024;
        if (e < E) {
            int p = lbase[mybkt[j]] + myrank[j];
            pos[e] = p;
            uint_t src  = (uint_t)ei[e];                 // < 65536
            uint_t dstl = (uint_t)(ei[E + e] & (  (1 << NB_SHIFT) - 1));
            recs[p] = src | (dstl << 16);
        }
    }
}

// ---------------------------------------------------------------------------
// K7: copy ea rows (f32) to eabs (bf16) in sorted order. 8 lanes per row.
// ---------------------------------------------------------------------------
__global__ void copy_ea_kernel(const float* __restrict__ ea,
                               const int* __restrict__ pos,
                               ushort_t* __restrict__ eabs, int E8) {
    int gid = blockIdx.x * blockDim.x + threadIdx.x;
    if (gid >= E8) return;
    int e = gid >> 3, seg = gid & 7;
    int p = pos[e];
    const float4* s = (const float4*)ea + (size_t)e * 16 + seg * 2;
    float4 v0 = s[0], v1 = s[1];
    uint4 w;
    w.x = pack2(v0.x, v0.y);
    w.y = pack2(v0.z, v0.w);
    w.z = pack2(v1.x, v1.y);
    w.w = pack2(v1.z, v1.w);
    *((uint4*)&eabs[(size_t)p * 64 + seg * 8]) = w;
}

// ---------------------------------------------------------------------------
// K8a: per-tile msg GEMM. One wave per (16-edge tile, 64-ch half) -> 75k
// independent one-shot waves, no LDS, no barriers, no serial loop. The random
// u-gather latency is hidden by TLP instead of a per-wave dependent chain.
// msg = leaky_relu(u[src] + eabs @ WemT16), streamed to msgl in sorted order.
// ---------------------------------------------------------------------------
__global__ __launch_bounds__(256) void msg_kernel(
        const ushort_t* __restrict__ eabs, const uint_t* __restrict__ recs,
        const ushort_t* __restrict__ WemT16, const float* __restrict__ u,
        float* __restrict__ msgl, int E) {
    int tid = threadIdx.x;
    int g = blockIdx.x * 4 + (tid >> 6);     // global wave id
    int tile = g >> 1;
    int t16 = tile * 16;
    if (t16 >= E) return;
    int lane = tid & 63, l15 = lane & 15, quad = lane >> 4;
    int chBase = (g & 1) << 6;
    int m = E - t16; if (m > 16) m = 16;
    int row = l15 < m ? l15 : m - 1;

    // issue the gather-index load first (everything else is independent)
    uint_t rec = recs[t16 + row];

    bf16x8 a0 = __builtin_bit_cast(bf16x8,
        *((const uint4*)&eabs[(size_t)(t16 + row) * 64 + quad * 8]));
    bf16x8 a1 = __builtin_bit_cast(bf16x8,
        *((const uint4*)&eabs[(size_t)(t16 + row) * 64 + 32 + quad * 8]));

    bf16x8 B[4][2];
    #pragma unroll
    for (int ct = 0; ct < 4; ++ct)
        #pragma unroll
        for (int kk = 0; kk < 2; ++kk)
            B[ct][kk] = __builtin_bit_cast(bf16x8, *((const uint4*)
                &WemT16[(size_t)(chBase + ct * 16 + l15) * 64 + kk * 32 + quad * 8]));

    // u-gather: 4 rows per quad, 64B contiguous per (r,ct) segment
    float uv[4][4];
    #pragma unroll
    for (int r = 0; r < 4; ++r) {
        int mm = quad * 4 + r;
        uint_t rr = __shfl(rec, mm);
        int sr = rr & 0xFFFF;
        if (mm < m) {
            #pragma unroll
            for (int ct = 0; ct < 4; ++ct)
                uv[ct][r] = u[(size_t)sr * 128 + chBase + ct * 16 + l15];
        }
    }

    f32x4 acc[4] = {{0.f,0.f,0.f,0.f},{0.f,0.f,0.f,0.f},
                    {0.f,0.f,0.f,0.f},{0.f,0.f,0.f,0.f}};
    #pragma unroll
    for (int ct = 0; ct < 4; ++ct)
        acc[ct] = __builtin_amdgcn_mfma_f32_16x16x32_bf16(a0, B[ct][0], acc[ct], 0, 0, 0);
    #pragma unroll
    for (int ct = 0; ct < 4; ++ct)
        acc[ct] = __builtin_amdgcn_mfma_f32_16x16x32_bf16(a1, B[ct][1], acc[ct], 0, 0, 0);

    #pragma unroll
    for (int r = 0; r < 4; ++r) {
        int mm = quad * 4 + r;
        if (mm < m) {
            #pragma unroll
            for (int ct = 0; ct < 4; ++ct) {
                float msg = acc[ct][r] + uv[ct][r];
                msg = msg > 0.f ? msg : 0.01f * msg;
                msgl[(size_t)(t16 + mm) * 128 + chBase + ct * 16 + l15] = msg;
            }
        }
    }
}

// ---------------------------------------------------------------------------
// K8b: streaming per-bucket segment sum of msgl + fused sigmoid*relu(beta).
// 512 threads: quarter q = tid>>7 owns p = s0+q, s0+q+4, ... ; thread (q,ch)
// is the ONLY writer of accum[q][*][ch] -> race-free non-atomic LDS adds.
// Reads are fully sequential/coalesced (256B per wave per edge).
// ---------------------------------------------------------------------------
__global__ __launch_bounds__(512) void segsum_kernel(
        const float* __restrict__ msgl, const uint_t* __restrict__ recs,
        const int* __restrict__ start, const float* __restrict__ beta,
        float* __restrict__ out, int N) {
    __shared__ float accum[4][16][128];     // 32 KiB
    int tid = threadIdx.x;
    int b = blockIdx.x;
    int base = b << NB_SHIFT;

    for (int li = tid; li < 4 * 16 * 128; li += 512) ((float*)accum)[li] = 0.f;
    __syncthreads();

    int q = tid >> 7, ch = tid & 127;
    int s0 = start[b], s1 = start[b + 1];
    for (int p = s0 + q; p < s1; p += 4) {
        int dstl = (int)(recs[p] >> 16);
        accum[q][dstl][ch] += msgl[(size_t)p * 128 + ch];
    }
    __syncthreads();

    float rb = beta[0];
    rb = rb > 0.f ? rb : 0.f;
    // 512 threads x one float4 = 16 nodes x 128 ch
    int r = tid >> 5, c4 = tid & 31;
    int n = base + r;
    if (n < N) {
        float4 v0 = *((float4*)&accum[0][r][c4 * 4]);
        float4 v1 = *((float4*)&accum[1][r][c4 * 4]);
        float4 v2 = *((float4*)&accum[2][r][c4 * 4]);
        float4 v3 = *((float4*)&accum[3][r][c4 * 4]);
        float4 v;
        v.x = v0.x + v1.x + v2.x + v3.x;
        v.y = v0.y + v1.y + v2.y + v3.y;
        v.z = v0.z + v1.z + v2.z + v3.z;
        v.w = v0.w + v1.w + v2.w + v3.w;
        v.x = rb / (1.f + __expf(-v.x));
        v.y = rb / (1.f + __expf(-v.y));
        v.z = rb / (1.f + __expf(-v.z));
        v.w = rb / (1.f + __expf(-v.w));
        ((float4*)out)[(size_t)n * 32 + c4] = v;
    }
}

// ---------------------------------------------------------------------------
// K8 (fallback): R6 fused per-bucket kernel, kept verbatim for the case where
// the workspace cannot hold msgl.
// ---------------------------------------------------------------------------
__global__ __launch_bounds__(256, 4) void edge_bucket_kernel(
        const ushort_t* __restrict__ eabs, const uint_t* __restrict__ recs,
        const ushort_t* __restrict__ WemT16, const float* __restrict__ u,
        const int* __restrict__ start, const float* __restrict__ beta,
        float* __restrict__ out, int N) {
    __shared__ __align__(16) float accum[16 * 132];   // 8448 B

    int tid = threadIdx.x;
    int b = blockIdx.x;
    int base = b << NB_SHIFT;

    for (int li = tid; li < 16 * 132; li += 256) accum[li] = 0.f;

    int lane = tid & 63, w = tid >> 6;
    int l15 = lane & 15, quad = lane >> 4;
    int chBase = (w >> 1) << 6;

    bf16x8 B[4][2];
    #pragma unroll
    for (int ct = 0; ct < 4; ++ct)
        #pragma unroll
        for (int kk = 0; kk < 2; ++kk)
            B[ct][kk] = __builtin_bit_cast(bf16x8, *((const uint4*)
                &WemT16[(size_t)(chBase + ct * 16 + l15) * 64 + kk * 32 + quad * 8]));

    __syncthreads();   // accum zeroed

    int s0 = start[b], s1 = start[b + 1];
    int t = s0 + ((w & 1) << 4);

    if (t < s1) {
        int m = s1 - t; if (m > 16) m = 16;
        int row = l15 < m ? l15 : m - 1;
        uint_t rec = recs[t + row];
        bf16x8 a0 = __builtin_bit_cast(bf16x8,
            *((const uint4*)&eabs[(size_t)(t + row) * 64 + quad * 8]));
        bf16x8 a1 = __builtin_bit_cast(bf16x8,
            *((const uint4*)&eabs[(size_t)(t + row) * 64 + 32 + quad * 8]));

        while (t < s1) {
            int tn = t + 32;
            uint_t recn = 0;
            bf16x8 a0n = a0, a1n = a1;
            int mn = 0;
            if (tn < s1) {
                mn = s1 - tn; if (mn > 16) mn = 16;
                int rown = l15 < mn ? l15 : mn - 1;
                recn = recs[tn + rown];
                a0n = __builtin_bit_cast(bf16x8,
                    *((const uint4*)&eabs[(size_t)(tn + rown) * 64 + quad * 8]));
                a1n = __builtin_bit_cast(bf16x8,
                    *((const uint4*)&eabs[(size_t)(tn + rown) * 64 + 32 + quad * 8]));
            }

            int dr[4]; float uv[4][4];
            #pragma unroll
            for (int r = 0; r < 4; ++r) {
                int mm = quad * 4 + r;
                uint_t rr = __shfl(rec, mm);
                int sr = rr & 0xFFFF;
                dr[r] = rr >> 16;
                if (mm < m) {
                    #pragma unroll
                    for (int ct = 0; ct < 4; ++ct)
                        uv[ct][r] = u[(size_t)sr * 128 + chBase + ct * 16 + l15];
                }
            }

            f32x4 acc[4] = {{0.f,0.f,0.f,0.f},{0.f,0.f,0.f,0.f},
                            {0.f,0.f,0.f,0.f},{0.f,0.f,0.f,0.f}};
            #pragma unroll
            for (int ct = 0; ct < 4; ++ct)
                acc[ct] = __builtin_amdgcn_mfma_f32_16x16x32_bf16(a0, B[ct][0], acc[ct], 0, 0, 0);
            #pragma unroll
            for (int ct = 0; ct < 4; ++ct)
                acc[ct] = __builtin_amdgcn_mfma_f32_16x16x32_bf16(a1, B[ct][1], acc[ct], 0, 0, 0);

            #pragma unroll
            for (int r = 0; r < 4; ++r) {
                int mm = quad * 4 + r;
                if (mm < m) {
                    #pragma unroll
                    for (int ct = 0; ct < 4; ++ct) {
                        float msg = acc[ct][r] + uv[ct][r];
                        msg = msg > 0.f ? msg : 0.01f * msg;
                        atomicAdd(&accum[dr[r] * 132 + chBase + ct * 16 + l15], msg);
                    }
                }
            }

            t = tn; m = mn; rec = recn; a0 = a0n; a1 = a1n;
        }
    }
    __syncthreads();

    float rb = beta[0];
    rb = rb > 0.f ? rb : 0.f;
    #pragma unroll
    for (int i = 0; i < 2; ++i) {
        int li = tid + i * 256;
        int r = li >> 5, c4 = li & 31;
        int n = base + r;
        if (n < N) {
            float4 v = *((float4*)&accum[r * 132 + c4 * 4]);
            v.x = rb / (1.f + __expf(-v.x));
            v.y = rb / (1.f + __expf(-v.y));
            v.z = rb / (1.f + __expf(-v.z));
            v.w = rb / (1.f + __expf(-v.w));
            ((float4*)out)[(size_t)n * 32 + c4] = v;
        }
    }
}

// ---------------------------------------------------------------------------
extern "C" void kernel_launch(void* const* d_in, const int* in_sizes, int n_in,
                              void* d_out, int out_size, void* d_ws, size_t ws_size,
                              hipStream_t stream) {
    const float* x    = (const float*)d_in[0];
    const int*   ei   = (const int*)d_in[1];
    const float* ea   = (const float*)d_in[2];
    const float* Wx   = (const float*)d_in[3];
    const float* bx   = (const float*)d_in[4];
    const float* We   = (const float*)d_in[5];
    const float* be   = (const float*)d_in[6];
    const float* Wm   = (const float*)d_in[7];
    const float* bm   = (const float*)d_in[8];
    const float* beta = (const float*)d_in[9];

    int N = in_sizes[0] / 128;   // 50000
    int E = in_sizes[2] / 64;    // 600000

    float* out = (float*)d_out;

    // workspace layout (bytes)
    char* ws = (char*)d_ws;
    ushort_t* WxmT16 = (ushort_t*)(ws);                    // 32768
    ushort_t* WemT16 = (ushort_t*)(ws + 32768);            // 16384
    float*    bf     = (float*)(ws + 49152);               // 512
    float*    u      = (float*)(ws + 65536);               // 25.6 MB
    size_t off = 65536 + (size_t)N * 128 * 4;
    ushort_t* xb   = (ushort_t*)(ws + off);                // 12.8 MB
    off += (size_t)N * 128 * 2;
    ushort_t* eabs = (ushort_t*)(ws + off);                // 76.8 MB
    off += (size_t)E * 64 * 2;
    uint_t* recs   = (uint_t*)(ws + off);                  // 2.4 MB
    off += (size_t)E * 4;
    int* pos       = (int*)(ws + off);                     // 2.4 MB
    off += (size_t)E * 4;
    int* cnt       = (int*)(ws + off);                     // NB ints
    int* startb    = (int*)(ws + off + 16384);             // NB+1 ints
    int* cur       = (int*)(ws + off + 32768);             // NB ints
    size_t msgl_off = off + 49152;
    float* msgl    = (float*)(ws + msgl_off);              // 307.2 MB (optional)
    size_t need    = msgl_off + (size_t)E * 128 * 4;

    hipMemsetAsync(cnt, 0, (size_t)NB * sizeof(int), stream);

    fuse_weights_kernel<<<(24704 + 255) / 256, 256, 0, stream>>>(
        Wx, bx, We, be, Wm, bm, WxmT16, WemT16, bf);

    int nx8 = N * 128 / 8;   // 800000
    convert_x_kernel<<<(nx8 + 255) / 256, 256, 0, stream>>>(x, xb, nx8);

    node_gemm_kernel<<<(N / 16 * 2 + 3) / 4, 256, 0, stream>>>(
        xb, WxmT16, bf, u, N);

    int nbBlocks = (E + 8191) / 8192;   // 74
    hist_kernel<<<nbBlocks, 1024, 0, stream>>>(ei, cnt, E);
    scan_kernel<<<1, 1024, 0, stream>>>(cnt, startb, cur, NB, E);
    binpos_kernel<<<nbBlocks, 1024, 0, stream>>>(ei, cur, pos, recs, E);

    int E8 = E * 8;   // 4.8M
    copy_ea_kernel<<<(E8 + 255) / 256, 256, 0, stream>>>(ea, pos, eabs, E8);

    if (ws_size >= need) {
        int ntiles = (E + 15) / 16;                 // 37500
        int nwaves = ntiles * 2;                    // 75000
        msg_kernel<<<(nwaves + 3) / 4, 256, 0, stream>>>(
            eabs, recs, WemT16, u, msgl, E);
        segsum_kernel<<<NB, 512, 0, stream>>>(
            msgl, recs, startb, beta, out, N);
    } else {
        edge_bucket_kernel<<<NB, 256, 0, stream>>>(
            eabs, recs, WemT16, u, startb, beta, out, N);
    }
}

// Round 2
// 526.276 us; speedup vs baseline: 1.4224x; 1.1392x over previous
//
#include <hip/hip_runtime.h>

// N=50000, E=600000, IN_CH=128, EDGE_DIM=64, OUT_CH=128
// edge_index delivered as int32.
//
// R8: move the u[src] gather out of the GEMM kernel into the reduction.
//   K8a msg_stream : PURE streaming MFMA GEMM eabs@WemT -> msgl (bf16,
//                    pre-activation, sorted order). No random access at all.
//   K8b segsum     : per bucket, per edge p: one coalesced 256B row gather of
//                    ub[src] (bf16) + sequential msgl row + leaky + race-free
//                    LDS accumulate + fused sigmoid*relu(beta).
// u is stored bf16 with the fused bias folded in (halves gather lines);
// convert_x is folded into node_gemm (reads f32 x, identical RNE rounding).

#define NB 3125
#define NB_SHIFT 4
#define TPW 4   // tiles per wave in msg_stream

typedef __bf16 bf16x8 __attribute__((ext_vector_type(8)));
typedef float  f32x4  __attribute__((ext_vector_type(4)));
typedef unsigned short ushort_t;
typedef unsigned int   uint_t;

__device__ __forceinline__ ushort_t f2b(float f) {   // RNE f32->bf16
    uint_t u = __float_as_uint(f);
    u += 0x7FFF + ((u >> 16) & 1);
    return (ushort_t)(u >> 16);
}
__device__ __forceinline__ uint_t pack2(float a, float b) {
    return (uint_t)f2b(a) | ((uint_t)f2b(b) << 16);
}
__device__ __forceinline__ float b2f(ushort_t v) {
    return __uint_as_float((uint_t)v << 16);
}

// ---------------------------------------------------------------------------
// K1: fold weights -> bf16 k-major tables + f32 bias.
// ---------------------------------------------------------------------------
__global__ void fuse_weights_kernel(const float* __restrict__ Wx,
                                    const float* __restrict__ bx,
                                    const float* __restrict__ We,
                                    const float* __restrict__ be,
                                    const float* __restrict__ Wm,
                                    const float* __restrict__ bm,
                                    ushort_t* __restrict__ WxmT16,
                                    ushort_t* __restrict__ WemT16,
                                    float* __restrict__ bf) {
    int idx = blockIdx.x * blockDim.x + threadIdx.x;
    if (idx < 128 * 128) {
        int r = idx >> 7, c = idx & 127;       // r=k, c=ch
        float acc = 0.f;
        #pragma unroll 8
        for (int j = 0; j < 128; ++j) acc += Wx[r * 128 + j] * Wm[j * 128 + c];
        WxmT16[c * 128 + r] = f2b(acc);
    } else if (idx < 128 * 128 + 64 * 128) {
        int t = idx - 128 * 128;
        int r = t >> 7, c = t & 127;           // r=k(<64), c=ch
        float acc = 0.f;
        #pragma unroll 8
        for (int j = 0; j < 128; ++j) acc += We[r * 128 + j] * Wm[(128 + j) * 128 + c];
        WemT16[c * 64 + r] = f2b(acc);
    } else if (idx < 128 * 128 + 64 * 128 + 128) {
        int c = idx - (128 * 128 + 64 * 128);
        float acc = bm[c];
        #pragma unroll 8
        for (int j = 0; j < 128; ++j)
            acc += bx[j] * Wm[j * 128 + c] + be[j] * Wm[(128 + j) * 128 + c];
        bf[c] = acc;
    }
}

// ---------------------------------------------------------------------------
// K3: ub = bf16(x @ WxmT16 + bf). Reads f32 x directly (in-register RNE
// convert, same bits as the old convert_x path), writes bf16 u.
// ---------------------------------------------------------------------------
__global__ __launch_bounds__(256) void node_gemm_kernel(
        const float* __restrict__ x, const ushort_t* __restrict__ WxmT16,
        const float* __restrict__ bf, ushort_t* __restrict__ ub, int N) {
    int tid = threadIdx.x;
    int g = blockIdx.x * 4 + (tid >> 6);
    if (g >= (N / 16) * 2) return;
    int lane = tid & 63, l15 = lane & 15, quad = lane >> 4;
    int n0 = (g >> 1) * 16;
    int chBase = (g & 1) * 64;

    bf16x8 B[4][4];
    #pragma unroll
    for (int ct = 0; ct < 4; ++ct)
        #pragma unroll
        for (int kk = 0; kk < 4; ++kk)
            B[ct][kk] = __builtin_bit_cast(bf16x8, *((const uint4*)
                &WxmT16[(size_t)(chBase + ct * 16 + l15) * 128 + kk * 32 + quad * 8]));

    bf16x8 A[4];
    #pragma unroll
    for (int kk = 0; kk < 4; ++kk) {
        const float4* s = (const float4*)&x[(size_t)(n0 + l15) * 128 + kk * 32 + quad * 8];
        float4 v0 = s[0], v1 = s[1];
        uint4 w;
        w.x = pack2(v0.x, v0.y);
        w.y = pack2(v0.z, v0.w);
        w.z = pack2(v1.x, v1.y);
        w.w = pack2(v1.z, v1.w);
        A[kk] = __builtin_bit_cast(bf16x8, w);
    }

    f32x4 acc[4] = {{0.f,0.f,0.f,0.f},{0.f,0.f,0.f,0.f},
                    {0.f,0.f,0.f,0.f},{0.f,0.f,0.f,0.f}};
    #pragma unroll
    for (int kk = 0; kk < 4; ++kk)
        #pragma unroll
        for (int ct = 0; ct < 4; ++ct)
            acc[ct] = __builtin_amdgcn_mfma_f32_16x16x32_bf16(A[kk], B[ct][kk], acc[ct], 0, 0, 0);

    #pragma unroll
    for (int ct = 0; ct < 4; ++ct) {
        float bias = bf[chBase + ct * 16 + l15];
        #pragma unroll
        for (int r = 0; r < 4; ++r)
            ub[(size_t)(n0 + quad * 4 + r) * 128 + chBase + ct * 16 + l15] =
                f2b(acc[ct][r] + bias);
    }
}

// ---------------------------------------------------------------------------
// K4: LDS-binned histogram of dst buckets.
// ---------------------------------------------------------------------------
__global__ __launch_bounds__(1024) void hist_kernel(
        const int* __restrict__ ei, int* __restrict__ cnt, int E) {
    __shared__ int lcnt[NB];
    int t = threadIdx.x;
    for (int i = t; i < NB; i += 1024) lcnt[i] = 0;
    __syncthreads();
    int base = blockIdx.x * 8192;
    #pragma unroll
    for (int j = 0; j < 8; ++j) {
        int e = base + t + j * 1024;
        if (e < E) atomicAdd(&lcnt[ei[E + e] >> NB_SHIFT], 1);
    }
    __syncthreads();
    for (int i = t; i < NB; i += 1024) {
        int c = lcnt[i];
        if (c) atomicAdd(&cnt[i], c);
    }
}

// ---------------------------------------------------------------------------
// K5: exclusive scan of cnt -> start, cur. Single block, 4 elems/thread.
// ---------------------------------------------------------------------------
__global__ __launch_bounds__(1024) void scan_kernel(
        const int* __restrict__ cnt, int* __restrict__ start,
        int* __restrict__ cur, int nb, int E) {
    __shared__ int tot[1024];
    int t = threadIdx.x;
    int v[4]; int sum = 0;
    #pragma unroll
    for (int j = 0; j < 4; ++j) {
        int i = t * 4 + j;
        v[j] = (i < nb) ? cnt[i] : 0;
        sum += v[j];
    }
    tot[t] = sum;
    __syncthreads();
    for (int d = 1; d < 1024; d <<= 1) {
        int val = tot[t];
        int add = (t >= d) ? tot[t - d] : 0;
        __syncthreads();
        tot[t] = val + add;
        __syncthreads();
    }
    int ex = (t == 0) ? 0 : tot[t - 1];
    #pragma unroll
    for (int j = 0; j < 4; ++j) {
        int i = t * 4 + j;
        if (i < nb) { start[i] = ex; cur[i] = ex; }
        ex += v[j];
    }
    if (t == 1023) start[nb] = ex;   // == E
}

// ---------------------------------------------------------------------------
// K6: block rank-and-reserve binning: pos[e], recs[pos] = src | dstl<<16.
// ---------------------------------------------------------------------------
__global__ __launch_bounds__(1024) void binpos_kernel(
        const int* __restrict__ ei, int* __restrict__ cur,
        int* __restrict__ pos, uint_t* __restrict__ recs, int E) {
    __shared__ int lcnt[NB];
    __shared__ int lbase[NB];
    int t = threadIdx.x;
    for (int i = t; i < NB; i += 1024) lcnt[i] = 0;
    __syncthreads();
    int base = blockIdx.x * 8192;
    int myrank[8], mybkt[8];
    #pragma unroll
    for (int j = 0; j < 8; ++j) {
        int e = base + t + j * 1024;
        if (e < E) {
            int b = ei[E + e] >> NB_SHIFT;
            mybkt[j] = b;
            myrank[j] = atomicAdd(&lcnt[b], 1);
        }
    }
    __syncthreads();
    for (int i = t; i < NB; i += 1024) {
        int c = lcnt[i];
        lbase[i] = c ? atomicAdd(&cur[i], c) : 0;
    }
    __syncthreads();
    #pragma unroll
    for (int j = 0; j < 8; ++j) {
        int e = base + t + j * 1024;
        if (e < E) {
            int p = lbase[mybkt[j]] + myrank[j];
            pos[e] = p;
            uint_t src  = (uint_t)ei[e];                 // < 65536
            uint_t dstl = (uint_t)(ei[E + e] & ((1 << NB_SHIFT) - 1));
            recs[p] = src | (dstl << 16);
        }
    }
}

// ---------------------------------------------------------------------------
// K7: copy ea rows (f32) to eabs (bf16) in sorted order. 8 lanes per row.
// ---------------------------------------------------------------------------
__global__ void copy_ea_kernel(const float* __restrict__ ea,
                               const int* __restrict__ pos,
                               ushort_t* __restrict__ eabs, int E8) {
    int gid = blockIdx.x * blockDim.x + threadIdx.x;
    if (gid >= E8) return;
    int e = gid >> 3, seg = gid & 7;
    int p = pos[e];
    const float4* s = (const float4*)ea + (size_t)e * 16 + seg * 2;
    float4 v0 = s[0], v1 = s[1];
    uint4 w;
    w.x = pack2(v0.x, v0.y);
    w.y = pack2(v0.z, v0.w);
    w.z = pack2(v1.x, v1.y);
    w.w = pack2(v1.z, v1.w);
    *((uint4*)&eabs[(size_t)p * 64 + seg * 8]) = w;
}

// ---------------------------------------------------------------------------
// K8a: PURE streaming edge GEMM: msgl = bf16(eabs @ WemT16), sorted order,
// pre-activation, bias excluded (it lives in ub). No gather, no recs, no
// branches in the hot path. TPW consecutive tiles per wave amortize B-frags.
// ---------------------------------------------------------------------------
__global__ __launch_bounds__(256) void msg_stream_kernel(
        const ushort_t* __restrict__ eabs, const ushort_t* __restrict__ WemT16,
        ushort_t* __restrict__ msgl, int E) {
    int tid = threadIdx.x;
    int g = blockIdx.x * 4 + (tid >> 6);     // global wave id
    int grp = g >> 1;
    int chBase = (g & 1) << 6;
    int t0 = grp * (TPW * 16);
    if (t0 >= E) return;
    int lane = tid & 63, l15 = lane & 15, quad = lane >> 4;

    bf16x8 B[4][2];
    #pragma unroll
    for (int ct = 0; ct < 4; ++ct)
        #pragma unroll
        for (int kk = 0; kk < 2; ++kk)
            B[ct][kk] = __builtin_bit_cast(bf16x8, *((const uint4*)
                &WemT16[(size_t)(chBase + ct * 16 + l15) * 64 + kk * 32 + quad * 8]));

    #pragma unroll
    for (int tt = 0; tt < TPW; ++tt) {
        int t16 = t0 + tt * 16;
        if (t16 >= E) break;
        bf16x8 a0 = __builtin_bit_cast(bf16x8,
            *((const uint4*)&eabs[(size_t)(t16 + l15) * 64 + quad * 8]));
        bf16x8 a1 = __builtin_bit_cast(bf16x8,
            *((const uint4*)&eabs[(size_t)(t16 + l15) * 64 + 32 + quad * 8]));

        f32x4 acc[4] = {{0.f,0.f,0.f,0.f},{0.f,0.f,0.f,0.f},
                        {0.f,0.f,0.f,0.f},{0.f,0.f,0.f,0.f}};
        #pragma unroll
        for (int ct = 0; ct < 4; ++ct)
            acc[ct] = __builtin_amdgcn_mfma_f32_16x16x32_bf16(a0, B[ct][0], acc[ct], 0, 0, 0);
        #pragma unroll
        for (int ct = 0; ct < 4; ++ct)
            acc[ct] = __builtin_amdgcn_mfma_f32_16x16x32_bf16(a1, B[ct][1], acc[ct], 0, 0, 0);

        #pragma unroll
        for (int r = 0; r < 4; ++r) {
            int row = t16 + quad * 4 + r;
            #pragma unroll
            for (int ct = 0; ct < 4; ++ct)
                msgl[(size_t)row * 128 + chBase + ct * 16 + l15] = f2b(acc[ct][r]);
        }
    }
}

// ---------------------------------------------------------------------------
// K8b: per-bucket segment sum. Per edge p: coalesced 256B bf16 row gather of
// ub[src] + sequential msgl row + leaky, race-free LDS accumulate (thread
// (q,ch) is the only writer of accum[q][*][ch]), fused sigmoid*relu(beta).
// ---------------------------------------------------------------------------
__global__ __launch_bounds__(512) void segsum_kernel(
        const ushort_t* __restrict__ msgl, const ushort_t* __restrict__ ub,
        const uint_t* __restrict__ recs, const int* __restrict__ start,
        const float* __restrict__ beta, float* __restrict__ out, int N) {
    __shared__ float accum[4][16][128];     // 32 KiB
    int tid = threadIdx.x;
    int b = blockIdx.x;
    int base = b << NB_SHIFT;

    for (int li = tid; li < 4 * 16 * 128; li += 512) ((float*)accum)[li] = 0.f;
    __syncthreads();

    int q = tid >> 7, ch = tid & 127;
    int s0 = start[b], s1 = start[b + 1];

    int p = s0 + q;
    uint_t rec = (p < s1) ? recs[p] : 0u;
    while (p < s1) {
        int pn = p + 4;
        uint_t recn = (pn < s1) ? recs[pn] : 0u;   // prefetch next index
        int sr = (int)(rec & 0xFFFF);
        int dl = (int)(rec >> 16);                 // 4-bit dst-local
        float mv  = b2f(msgl[(size_t)p * 128 + ch]);
        float uvv = b2f(ub[(size_t)sr * 128 + ch]);
        float m = mv + uvv;
        m = m > 0.f ? m : 0.01f * m;
        accum[q][dl][ch] += m;
        p = pn; rec = recn;
    }
    __syncthreads();

    float rb = beta[0];
    rb = rb > 0.f ? rb : 0.f;
    // 512 threads x one float4 = 16 nodes x 128 ch
    int r = tid >> 5, c4 = tid & 31;
    int n = base + r;
    if (n < N) {
        float4 v0 = *((float4*)&accum[0][r][c4 * 4]);
        float4 v1 = *((float4*)&accum[1][r][c4 * 4]);
        float4 v2 = *((float4*)&accum[2][r][c4 * 4]);
        float4 v3 = *((float4*)&accum[3][r][c4 * 4]);
        float4 v;
        v.x = v0.x + v1.x + v2.x + v3.x;
        v.y = v0.y + v1.y + v2.y + v3.y;
        v.z = v0.z + v1.z + v2.z + v3.z;
        v.w = v0.w + v1.w + v2.w + v3.w;
        v.x = rb / (1.f + __expf(-v.x));
        v.y = rb / (1.f + __expf(-v.y));
        v.z = rb / (1.f + __expf(-v.z));
        v.w = rb / (1.f + __expf(-v.w));
        ((float4*)out)[(size_t)n * 32 + c4] = v;
    }
}

// ---------------------------------------------------------------------------
extern "C" void kernel_launch(void* const* d_in, const int* in_sizes, int n_in,
                              void* d_out, int out_size, void* d_ws, size_t ws_size,
                              hipStream_t stream) {
    const float* x    = (const float*)d_in[0];
    const int*   ei   = (const int*)d_in[1];
    const float* ea   = (const float*)d_in[2];
    const float* Wx   = (const float*)d_in[3];
    const float* bx   = (const float*)d_in[4];
    const float* We   = (const float*)d_in[5];
    const float* be   = (const float*)d_in[6];
    const float* Wm   = (const float*)d_in[7];
    const float* bm   = (const float*)d_in[8];
    const float* beta = (const float*)d_in[9];

    int N = in_sizes[0] / 128;   // 50000
    int E = in_sizes[2] / 64;    // 600000

    float* out = (float*)d_out;

    // workspace layout (bytes)
    char* ws = (char*)d_ws;
    ushort_t* WxmT16 = (ushort_t*)(ws);                    // 32768
    ushort_t* WemT16 = (ushort_t*)(ws + 32768);            // 16384
    float*    bf     = (float*)(ws + 49152);               // 512
    ushort_t* ub     = (ushort_t*)(ws + 65536);            // 12.8 MB (bf16)
    size_t off = 65536 + (size_t)N * 128 * 2;
    ushort_t* eabs = (ushort_t*)(ws + off);                // 76.8 MB
    off += (size_t)E * 64 * 2;
    uint_t* recs   = (uint_t*)(ws + off);                  // 2.4 MB
    off += (size_t)E * 4;
    int* pos       = (int*)(ws + off);                     // 2.4 MB
    off += (size_t)E * 4;
    int* cnt       = (int*)(ws + off);                     // NB ints
    int* startb    = (int*)(ws + off + 16384);             // NB+1 ints
    int* cur       = (int*)(ws + off + 32768);             // NB ints
    ushort_t* msgl = (ushort_t*)(ws + off + 49152);        // 153.6 MB (bf16)

    hipMemsetAsync(cnt, 0, (size_t)NB * sizeof(int), stream);

    fuse_weights_kernel<<<(24704 + 255) / 256, 256, 0, stream>>>(
        Wx, bx, We, be, Wm, bm, WxmT16, WemT16, bf);

    node_gemm_kernel<<<(N / 16 * 2 + 3) / 4, 256, 0, stream>>>(
        x, WxmT16, bf, ub, N);

    int nbBlocks = (E + 8191) / 8192;   // 74
    hist_kernel<<<nbBlocks, 1024, 0, stream>>>(ei, cnt, E);
    scan_kernel<<<1, 1024, 0, stream>>>(cnt, startb, cur, NB, E);
    binpos_kernel<<<nbBlocks, 1024, 0, stream>>>(ei, cur, pos, recs, E);

    int E8 = E * 8;   // 4.8M
    copy_ea_kernel<<<(E8 + 255) / 256, 256, 0, stream>>>(ea, pos, eabs, E8);

    int ntile  = (E + 15) / 16;                    // 37500
    int ngrp   = (ntile + TPW - 1) / TPW;          // 9375
    int nwaves = ngrp * 2;                         // 18750
    msg_stream_kernel<<<(nwaves + 3) / 4, 256, 0, stream>>>(
        eabs, WemT16, msgl, E);

    segsum_kernel<<<NB, 512, 0, stream>>>(
        msgl, ub, recs, startb, beta, out, N);
}

// Round 3
// 481.009 us; speedup vs baseline: 1.5563x; 1.0941x over previous
//
#include <hip/hip_runtime.h>

// N=50000, E=600000, IN_CH=128, EDGE_DIM=64, OUT_CH=128
// edge_index delivered as int32.
//
// R9: register-accumulator reduction via finer sort.
//   - Sort refined to 2-node buckets (NB=25000, NB_SHIFT=1). hist/binpos use
//     one 100KB LDS array (in-place count->base trick in binpos).
//   - segsum: ONE WAVE PER BUCKET, accumulators in registers (2 nodes x 4ch
//     per lane, fmac-selected by dst bit). No LDS, no atomics, no RMW chain.
//     uint2 loads: 2 edges in flight per wave-iteration, rec prefetched.
//   - copy_ea/eabs ELIMINATED: msg_stream reads ea f32 directly (contiguous
//     unsorted tiles), converts in-register, scatter-stores msgl rows by pos.

#define NB 25000
#define NB_SHIFT 1
#define TPW 4   // tiles per wave in msg_stream

typedef __bf16 bf16x8 __attribute__((ext_vector_type(8)));
typedef float  f32x4  __attribute__((ext_vector_type(4)));
typedef unsigned short ushort_t;
typedef unsigned int   uint_t;

__device__ __forceinline__ ushort_t f2b(float f) {   // RNE f32->bf16
    uint_t u = __float_as_uint(f);
    u += 0x7FFF + ((u >> 16) & 1);
    return (ushort_t)(u >> 16);
}
__device__ __forceinline__ uint_t pack2(float a, float b) {
    return (uint_t)f2b(a) | ((uint_t)f2b(b) << 16);
}

// ---------------------------------------------------------------------------
// K1: fold weights -> bf16 k-major tables + f32 bias.
// ---------------------------------------------------------------------------
__global__ void fuse_weights_kernel(const float* __restrict__ Wx,
                                    const float* __restrict__ bx,
                                    const float* __restrict__ We,
                                    const float* __restrict__ be,
                                    const float* __restrict__ Wm,
                                    const float* __restrict__ bm,
                                    ushort_t* __restrict__ WxmT16,
                                    ushort_t* __restrict__ WemT16,
                                    float* __restrict__ bf) {
    int idx = blockIdx.x * blockDim.x + threadIdx.x;
    if (idx < 128 * 128) {
        int r = idx >> 7, c = idx & 127;       // r=k, c=ch
        float acc = 0.f;
        #pragma unroll 8
        for (int j = 0; j < 128; ++j) acc += Wx[r * 128 + j] * Wm[j * 128 + c];
        WxmT16[c * 128 + r] = f2b(acc);
    } else if (idx < 128 * 128 + 64 * 128) {
        int t = idx - 128 * 128;
        int r = t >> 7, c = t & 127;           // r=k(<64), c=ch
        float acc = 0.f;
        #pragma unroll 8
        for (int j = 0; j < 128; ++j) acc += We[r * 128 + j] * Wm[(128 + j) * 128 + c];
        WemT16[c * 64 + r] = f2b(acc);
    } else if (idx < 128 * 128 + 64 * 128 + 128) {
        int c = idx - (128 * 128 + 64 * 128);
        float acc = bm[c];
        #pragma unroll 8
        for (int j = 0; j < 128; ++j)
            acc += bx[j] * Wm[j * 128 + c] + be[j] * Wm[(128 + j) * 128 + c];
        bf[c] = acc;
    }
}

// ---------------------------------------------------------------------------
// K3: ub = bf16(x @ WxmT16 + bf). Reads f32 x directly (in-register RNE
// convert), writes bf16 u with bias folded in.
// ---------------------------------------------------------------------------
__global__ __launch_bounds__(256) void node_gemm_kernel(
        const float* __restrict__ x, const ushort_t* __restrict__ WxmT16,
        const float* __restrict__ bf, ushort_t* __restrict__ ub, int N) {
    int tid = threadIdx.x;
    int g = blockIdx.x * 4 + (tid >> 6);
    if (g >= (N / 16) * 2) return;
    int lane = tid & 63, l15 = lane & 15, quad = lane >> 4;
    int n0 = (g >> 1) * 16;
    int chBase = (g & 1) * 64;

    bf16x8 B[4][4];
    #pragma unroll
    for (int ct = 0; ct < 4; ++ct)
        #pragma unroll
        for (int kk = 0; kk < 4; ++kk)
            B[ct][kk] = __builtin_bit_cast(bf16x8, *((const uint4*)
                &WxmT16[(size_t)(chBase + ct * 16 + l15) * 128 + kk * 32 + quad * 8]));

    bf16x8 A[4];
    #pragma unroll
    for (int kk = 0; kk < 4; ++kk) {
        const float4* s = (const float4*)&x[(size_t)(n0 + l15) * 128 + kk * 32 + quad * 8];
        float4 v0 = s[0], v1 = s[1];
        uint4 w;
        w.x = pack2(v0.x, v0.y);
        w.y = pack2(v0.z, v0.w);
        w.z = pack2(v1.x, v1.y);
        w.w = pack2(v1.z, v1.w);
        A[kk] = __builtin_bit_cast(bf16x8, w);
    }

    f32x4 acc[4] = {{0.f,0.f,0.f,0.f},{0.f,0.f,0.f,0.f},
                    {0.f,0.f,0.f,0.f},{0.f,0.f,0.f,0.f}};
    #pragma unroll
    for (int kk = 0; kk < 4; ++kk)
        #pragma unroll
        for (int ct = 0; ct < 4; ++ct)
            acc[ct] = __builtin_amdgcn_mfma_f32_16x16x32_bf16(A[kk], B[ct][kk], acc[ct], 0, 0, 0);

    #pragma unroll
    for (int ct = 0; ct < 4; ++ct) {
        float bias = bf[chBase + ct * 16 + l15];
        #pragma unroll
        for (int r = 0; r < 4; ++r)
            ub[(size_t)(n0 + quad * 4 + r) * 128 + chBase + ct * 16 + l15] =
                f2b(acc[ct][r] + bias);
    }
}

// ---------------------------------------------------------------------------
// K4: LDS-binned histogram of dst buckets (25000 bins, 100KB LDS).
// ---------------------------------------------------------------------------
__global__ __launch_bounds__(1024) void hist_kernel(
        const int* __restrict__ ei, int* __restrict__ cnt, int E) {
    __shared__ int lcnt[NB];
    int t = threadIdx.x;
    for (int i = t; i < NB; i += 1024) lcnt[i] = 0;
    __syncthreads();
    int base = blockIdx.x * 8192;
    #pragma unroll
    for (int j = 0; j < 8; ++j) {
        int e = base + t + j * 1024;
        if (e < E) atomicAdd(&lcnt[ei[E + e] >> NB_SHIFT], 1);
    }
    __syncthreads();
    for (int i = t; i < NB; i += 1024) {
        int c = lcnt[i];
        if (c) atomicAdd(&cnt[i], c);
    }
}

// ---------------------------------------------------------------------------
// K5: exclusive scan of cnt -> start, cur. Single block, 25 elems/thread.
// ---------------------------------------------------------------------------
__global__ __launch_bounds__(1024) void scan_kernel(
        const int* __restrict__ cnt, int* __restrict__ start,
        int* __restrict__ cur, int nb, int E) {
    __shared__ int tot[1024];
    int t = threadIdx.x;
    int v[25]; int sum = 0;
    #pragma unroll
    for (int j = 0; j < 25; ++j) {
        int i = t * 25 + j;
        v[j] = (i < nb) ? cnt[i] : 0;
        sum += v[j];
    }
    tot[t] = sum;
    __syncthreads();
    for (int d = 1; d < 1024; d <<= 1) {
        int val = tot[t];
        int add = (t >= d) ? tot[t - d] : 0;
        __syncthreads();
        tot[t] = val + add;
        __syncthreads();
    }
    int ex = (t == 0) ? 0 : tot[t - 1];
    #pragma unroll
    for (int j = 0; j < 25; ++j) {
        int i = t * 25 + j;
        if (i < nb) { start[i] = ex; cur[i] = ex; }
        ex += v[j];
    }
    if (t == 1023) start[nb] = ex;   // == E
}

// ---------------------------------------------------------------------------
// K6: block rank-and-reserve binning (single 100KB LDS array, in-place
// count -> base). pos[e], recs[pos] = src | dstl<<16 (dstl = 1 bit).
// ---------------------------------------------------------------------------
__global__ __launch_bounds__(1024) void binpos_kernel(
        const int* __restrict__ ei, int* __restrict__ cur,
        int* __restrict__ pos, uint_t* __restrict__ recs, int E) {
    __shared__ int lcnt[NB];
    int t = threadIdx.x;
    for (int i = t; i < NB; i += 1024) lcnt[i] = 0;
    __syncthreads();
    int base = blockIdx.x * 8192;
    int myrank[8], mybkt[8];
    #pragma unroll
    for (int j = 0; j < 8; ++j) {
        int e = base + t + j * 1024;
        if (e < E) {
            int b = ei[E + e] >> NB_SHIFT;
            mybkt[j] = b;
            myrank[j] = atomicAdd(&lcnt[b], 1);
        }
    }
    __syncthreads();
    // in-place: lcnt[i] becomes the block's base for bucket i
    for (int i = t; i < NB; i += 1024) {
        int c = lcnt[i];
        lcnt[i] = c ? atomicAdd(&cur[i], c) : 0;
    }
    __syncthreads();
    #pragma unroll
    for (int j = 0; j < 8; ++j) {
        int e = base + t + j * 1024;
        if (e < E) {
            int p = lcnt[mybkt[j]] + myrank[j];
            pos[e] = p;
            uint_t src  = (uint_t)ei[e];                 // < 65536
            uint_t dstl = (uint_t)(ei[E + e] & ((1 << NB_SHIFT) - 1));
            recs[p] = src | (dstl << 16);
        }
    }
}

// ---------------------------------------------------------------------------
// K8a: streaming edge GEMM directly from ea (f32, contiguous unsorted tiles):
// msgl[pos[e]] = bf16(ea[e] @ WemT16). In-register f32->bf16 convert, MFMA,
// row-granular scatter store through pos. copy_ea/eabs eliminated.
// ---------------------------------------------------------------------------
__global__ __launch_bounds__(256) void msg_stream_kernel(
        const float* __restrict__ ea, const int* __restrict__ pos,
        const ushort_t* __restrict__ WemT16, ushort_t* __restrict__ msgl, int E) {
    int tid = threadIdx.x;
    int g = blockIdx.x * 4 + (tid >> 6);     // global wave id
    int grp = g >> 1;
    int chBase = (g & 1) << 6;
    int t0 = grp * (TPW * 16);
    if (t0 >= E) return;
    int lane = tid & 63, l15 = lane & 15, quad = lane >> 4;

    bf16x8 B[4][2];
    #pragma unroll
    for (int ct = 0; ct < 4; ++ct)
        #pragma unroll
        for (int kk = 0; kk < 2; ++kk)
            B[ct][kk] = __builtin_bit_cast(bf16x8, *((const uint4*)
                &WemT16[(size_t)(chBase + ct * 16 + l15) * 64 + kk * 32 + quad * 8]));

    #pragma unroll
    for (int tt = 0; tt < TPW; ++tt) {
        int t16 = t0 + tt * 16;
        if (t16 >= E) break;
        const float* rowp = &ea[(size_t)(t16 + l15) * 64];
        const float4* sA = (const float4*)(rowp + quad * 8);
        float4 v0 = sA[0], v1 = sA[1];
        uint4 w0;
        w0.x = pack2(v0.x, v0.y);
        w0.y = pack2(v0.z, v0.w);
        w0.z = pack2(v1.x, v1.y);
        w0.w = pack2(v1.z, v1.w);
        bf16x8 a0 = __builtin_bit_cast(bf16x8, w0);
        const float4* sB = (const float4*)(rowp + 32 + quad * 8);
        float4 v2 = sB[0], v3 = sB[1];
        uint4 w1;
        w1.x = pack2(v2.x, v2.y);
        w1.y = pack2(v2.z, v2.w);
        w1.z = pack2(v3.x, v3.y);
        w1.w = pack2(v3.z, v3.w);
        bf16x8 a1 = __builtin_bit_cast(bf16x8, w1);

        f32x4 acc[4] = {{0.f,0.f,0.f,0.f},{0.f,0.f,0.f,0.f},
                        {0.f,0.f,0.f,0.f},{0.f,0.f,0.f,0.f}};
        #pragma unroll
        for (int ct = 0; ct < 4; ++ct)
            acc[ct] = __builtin_amdgcn_mfma_f32_16x16x32_bf16(a0, B[ct][0], acc[ct], 0, 0, 0);
        #pragma unroll
        for (int ct = 0; ct < 4; ++ct)
            acc[ct] = __builtin_amdgcn_mfma_f32_16x16x32_bf16(a1, B[ct][1], acc[ct], 0, 0, 0);

        int4 pr = *(const int4*)&pos[t16 + quad * 4];
        int prr[4] = {pr.x, pr.y, pr.z, pr.w};
        #pragma unroll
        for (int r = 0; r < 4; ++r) {
            #pragma unroll
            for (int ct = 0; ct < 4; ++ct)
                msgl[(size_t)prr[r] * 128 + chBase + ct * 16 + l15] = f2b(acc[ct][r]);
        }
    }
}

// ---------------------------------------------------------------------------
// K8b: wave-per-bucket segment sum, accumulators in REGISTERS (2 nodes x
// 4 ch/lane, fmac-selected by the dst bit). uint2 loads, 2 edges per
// wave-iteration, rec prefetched. No LDS, no barriers, no atomics.
// ---------------------------------------------------------------------------
__global__ __launch_bounds__(256) void segsum_kernel(
        const ushort_t* __restrict__ msgl, const ushort_t* __restrict__ ub,
        const uint_t* __restrict__ recs, const int* __restrict__ start,
        const float* __restrict__ beta, float* __restrict__ out, int N) {
    int wid = blockIdx.x * 4 + (threadIdx.x >> 6);   // bucket id
    if (wid >= NB) return;
    int lane = threadIdx.x & 63;
    int half = lane >> 5;          // edge slot within iteration
    int c8 = lane & 31;            // channel group: ch 4*c8 .. 4*c8+3

    int s0 = start[wid], s1 = start[wid + 1];
    float a0[4] = {0.f, 0.f, 0.f, 0.f};
    float a1[4] = {0.f, 0.f, 0.f, 0.f};

    int p = s0 + half;
    uint_t rec = (p < s1) ? recs[p] : 0u;
    while (p < s1) {
        int pn = p + 2;
        uint_t recn = (pn < s1) ? recs[pn] : 0u;     // prefetch next index

        uint2 mv = *(const uint2*)&msgl[(size_t)p * 128 + (c8 << 2)];
        int sr = (int)(rec & 0xFFFFu);
        uint2 uv = *(const uint2*)&ub[(size_t)sr * 128 + (c8 << 2)];

        float w1 = (rec >> 16) ? 1.f : 0.f;
        float w0 = 1.f - w1;

        float m0 = __uint_as_float(mv.x << 16)         + __uint_as_float(uv.x << 16);
        float m1 = __uint_as_float(mv.x & 0xFFFF0000u) + __uint_as_float(uv.x & 0xFFFF0000u);
        float m2 = __uint_as_float(mv.y << 16)         + __uint_as_float(uv.y << 16);
        float m3 = __uint_as_float(mv.y & 0xFFFF0000u) + __uint_as_float(uv.y & 0xFFFF0000u);
        m0 = fmaxf(m0, 0.01f * m0);
        m1 = fmaxf(m1, 0.01f * m1);
        m2 = fmaxf(m2, 0.01f * m2);
        m3 = fmaxf(m3, 0.01f * m3);

        a0[0] += m0 * w0;  a1[0] += m0 * w1;
        a0[1] += m1 * w0;  a1[1] += m1 * w1;
        a0[2] += m2 * w0;  a1[2] += m2 * w1;
        a0[3] += m3 * w0;  a1[3] += m3 * w1;

        p = pn; rec = recn;
    }

    // combine the two half-wave edge slots
    #pragma unroll
    for (int j = 0; j < 4; ++j) {
        a0[j] += __shfl_xor(a0[j], 32);
        a1[j] += __shfl_xor(a1[j], 32);
    }

    float rb = beta[0];
    rb = rb > 0.f ? rb : 0.f;
    int n = (wid << 1) + half;       // half 0 -> node0, half 1 -> node1
    if (n < N) {
        float4 v;
        if (half == 0) {
            v.x = a0[0]; v.y = a0[1]; v.z = a0[2]; v.w = a0[3];
        } else {
            v.x = a1[0]; v.y = a1[1]; v.z = a1[2]; v.w = a1[3];
        }
        v.x = rb / (1.f + __expf(-v.x));
        v.y = rb / (1.f + __expf(-v.y));
        v.z = rb / (1.f + __expf(-v.z));
        v.w = rb / (1.f + __expf(-v.w));
        ((float4*)out)[(size_t)n * 32 + c8] = v;
    }
}

// ---------------------------------------------------------------------------
extern "C" void kernel_launch(void* const* d_in, const int* in_sizes, int n_in,
                              void* d_out, int out_size, void* d_ws, size_t ws_size,
                              hipStream_t stream) {
    const float* x    = (const float*)d_in[0];
    const int*   ei   = (const int*)d_in[1];
    const float* ea   = (const float*)d_in[2];
    const float* Wx   = (const float*)d_in[3];
    const float* bx   = (const float*)d_in[4];
    const float* We   = (const float*)d_in[5];
    const float* be   = (const float*)d_in[6];
    const float* Wm   = (const float*)d_in[7];
    const float* bm   = (const float*)d_in[8];
    const float* beta = (const float*)d_in[9];

    int N = in_sizes[0] / 128;   // 50000
    int E = in_sizes[2] / 64;    // 600000

    float* out = (float*)d_out;

    // workspace layout (bytes)
    char* ws = (char*)d_ws;
    ushort_t* WxmT16 = (ushort_t*)(ws);                    // 32768
    ushort_t* WemT16 = (ushort_t*)(ws + 32768);            // 16384
    float*    bf     = (float*)(ws + 49152);               // 512
    ushort_t* ub     = (ushort_t*)(ws + 65536);            // 12.8 MB (bf16)
    size_t off = 65536 + (size_t)N * 128 * 2;
    uint_t* recs   = (uint_t*)(ws + off);                  // 2.4 MB
    off += (size_t)E * 4;
    int* pos       = (int*)(ws + off);                     // 2.4 MB
    off += (size_t)E * 4;
    int* cnt       = (int*)(ws + off);                     // 100 KB
    int* startb    = (int*)(ws + off + 131072);            // 100 KB + 4
    int* cur       = (int*)(ws + off + 262144);            // 100 KB
    ushort_t* msgl = (ushort_t*)(ws + off + 393216);       // 153.6 MB (bf16)

    hipMemsetAsync(cnt, 0, (size_t)NB * sizeof(int), stream);

    fuse_weights_kernel<<<(24704 + 255) / 256, 256, 0, stream>>>(
        Wx, bx, We, be, Wm, bm, WxmT16, WemT16, bf);

    node_gemm_kernel<<<(N / 16 * 2 + 3) / 4, 256, 0, stream>>>(
        x, WxmT16, bf, ub, N);

    int nbBlocks = (E + 8191) / 8192;   // 74
    hist_kernel<<<nbBlocks, 1024, 0, stream>>>(ei, cnt, E);
    scan_kernel<<<1, 1024, 0, stream>>>(cnt, startb, cur, NB, E);
    binpos_kernel<<<nbBlocks, 1024, 0, stream>>>(ei, cur, pos, recs, E);

    int ntile  = (E + 15) / 16;                    // 37500
    int ngrp   = (ntile + TPW - 1) / TPW;          // 9375
    int nwaves = ngrp * 2;                         // 18750
    msg_stream_kernel<<<(nwaves + 3) / 4, 256, 0, stream>>>(
        ea, pos, WemT16, msgl, E);

    segsum_kernel<<<(NB + 3) / 4, 256, 0, stream>>>(
        msgl, ub, recs, startb, beta, out, N);
}

// Round 4
// 467.667 us; speedup vs baseline: 1.6007x; 1.0285x over previous
//
#include <hip/hip_runtime.h>

// N=50000, E=600000, IN_CH=128, EDGE_DIM=64, OUT_CH=128
// edge_index delivered as int32.
//
// R10: issue-efficiency pass on the two hot kernels.
//   - msg_stream: operand-SWAPPED MFMA (A=weight frag, B=edge frag) so each
//     lane holds 4 consecutive channels of ONE edge -> 4 packed uint2 stores
//     per tile (was 16 scalar b16 stores); straight-line 4-tile fast path
//     (E%64==0) so all loads hoist ahead of the MFMA/store cluster.
//   - node_gemm: same swap -> packed uint2 stores + float4 bias loads.
//   - segsum: 4 edges/iter (one per 16-lane quarter), uint4 (16B) row loads,
//     2-deep rec prefetch + 1-deep data pipeline, full-wave shfl reduce,
//     static-indexed epilogue.
//   - hist/binpos: 16384 edges per block (amortize 100KB LDS zero/flush).

#define NB 25000
#define NB_SHIFT 1
#define TPW 4   // tiles per wave in msg_stream

typedef __bf16 bf16x8 __attribute__((ext_vector_type(8)));
typedef float  f32x4  __attribute__((ext_vector_type(4)));
typedef unsigned short ushort_t;
typedef unsigned int   uint_t;

__device__ __forceinline__ ushort_t f2b(float f) {   // RNE f32->bf16
    uint_t u = __float_as_uint(f);
    u += 0x7FFF + ((u >> 16) & 1);
    return (ushort_t)(u >> 16);
}
__device__ __forceinline__ uint_t pack2(float a, float b) {
    return (uint_t)f2b(a) | ((uint_t)f2b(b) << 16);
}

// ---------------------------------------------------------------------------
// K1: fold weights -> bf16 k-major tables + f32 bias.
// ---------------------------------------------------------------------------
__global__ void fuse_weights_kernel(const float* __restrict__ Wx,
                                    const float* __restrict__ bx,
                                    const float* __restrict__ We,
                                    const float* __restrict__ be,
                                    const float* __restrict__ Wm,
                                    const float* __restrict__ bm,
                                    ushort_t* __restrict__ WxmT16,
                                    ushort_t* __restrict__ WemT16,
                                    float* __restrict__ bf) {
    int idx = blockIdx.x * blockDim.x + threadIdx.x;
    if (idx < 128 * 128) {
        int r = idx >> 7, c = idx & 127;       // r=k, c=ch
        float acc = 0.f;
        #pragma unroll 8
        for (int j = 0; j < 128; ++j) acc += Wx[r * 128 + j] * Wm[j * 128 + c];
        WxmT16[c * 128 + r] = f2b(acc);
    } else if (idx < 128 * 128 + 64 * 128) {
        int t = idx - 128 * 128;
        int r = t >> 7, c = t & 127;           // r=k(<64), c=ch
        float acc = 0.f;
        #pragma unroll 8
        for (int j = 0; j < 128; ++j) acc += We[r * 128 + j] * Wm[(128 + j) * 128 + c];
        WemT16[c * 64 + r] = f2b(acc);
    } else if (idx < 128 * 128 + 64 * 128 + 128) {
        int c = idx - (128 * 128 + 64 * 128);
        float acc = bm[c];
        #pragma unroll 8
        for (int j = 0; j < 128; ++j)
            acc += bx[j] * Wm[j * 128 + c] + be[j] * Wm[(128 + j) * 128 + c];
        bf[c] = acc;
    }
}

// ---------------------------------------------------------------------------
// K3: ub = bf16(x @ WxmT16 + bf). Operand-swapped MFMA: C[ch, node] so each
// lane holds 4 consecutive channels of node l15 -> packed uint2 stores.
// ---------------------------------------------------------------------------
__global__ __launch_bounds__(256) void node_gemm_kernel(
        const float* __restrict__ x, const ushort_t* __restrict__ WxmT16,
        const float* __restrict__ bf, ushort_t* __restrict__ ub, int N) {
    int tid = threadIdx.x;
    int g = blockIdx.x * 4 + (tid >> 6);
    if (g >= (N / 16) * 2) return;
    int lane = tid & 63, l15 = lane & 15, quad = lane >> 4;
    int n0 = (g >> 1) * 16;
    int chBase = (g & 1) * 64;

    bf16x8 B[4][4];
    #pragma unroll
    for (int ct = 0; ct < 4; ++ct)
        #pragma unroll
        for (int kk = 0; kk < 4; ++kk)
            B[ct][kk] = __builtin_bit_cast(bf16x8, *((const uint4*)
                &WxmT16[(size_t)(chBase + ct * 16 + l15) * 128 + kk * 32 + quad * 8]));

    bf16x8 A[4];
    #pragma unroll
    for (int kk = 0; kk < 4; ++kk) {
        const float4* s = (const float4*)&x[(size_t)(n0 + l15) * 128 + kk * 32 + quad * 8];
        float4 v0 = s[0], v1 = s[1];
        uint4 w;
        w.x = pack2(v0.x, v0.y);
        w.y = pack2(v0.z, v0.w);
        w.z = pack2(v1.x, v1.y);
        w.w = pack2(v1.z, v1.w);
        A[kk] = __builtin_bit_cast(bf16x8, w);
    }

    f32x4 acc[4] = {{0.f,0.f,0.f,0.f},{0.f,0.f,0.f,0.f},
                    {0.f,0.f,0.f,0.f},{0.f,0.f,0.f,0.f}};
    #pragma unroll
    for (int kk = 0; kk < 4; ++kk)
        #pragma unroll
        for (int ct = 0; ct < 4; ++ct)   // SWAPPED: A=weight, B=node rows
            acc[ct] = __builtin_amdgcn_mfma_f32_16x16x32_bf16(B[ct][kk], A[kk], acc[ct], 0, 0, 0);

    #pragma unroll
    for (int ct = 0; ct < 4; ++ct) {
        int ch = chBase + ct * 16 + quad * 4;
        float4 bv = *(const float4*)&bf[ch];
        uint2 w;
        w.x = pack2(acc[ct][0] + bv.x, acc[ct][1] + bv.y);
        w.y = pack2(acc[ct][2] + bv.z, acc[ct][3] + bv.w);
        *((uint2*)&ub[(size_t)(n0 + l15) * 128 + ch]) = w;
    }
}

// ---------------------------------------------------------------------------
// K4: LDS-binned histogram of dst buckets (25000 bins, 100KB LDS).
// ---------------------------------------------------------------------------
__global__ __launch_bounds__(1024) void hist_kernel(
        const int* __restrict__ ei, int* __restrict__ cnt, int E) {
    __shared__ int lcnt[NB];
    int t = threadIdx.x;
    for (int i = t; i < NB; i += 1024) lcnt[i] = 0;
    __syncthreads();
    int base = blockIdx.x * 16384;
    #pragma unroll
    for (int j = 0; j < 16; ++j) {
        int e = base + t + j * 1024;
        if (e < E) atomicAdd(&lcnt[ei[E + e] >> NB_SHIFT], 1);
    }
    __syncthreads();
    for (int i = t; i < NB; i += 1024) {
        int c = lcnt[i];
        if (c) atomicAdd(&cnt[i], c);
    }
}

// ---------------------------------------------------------------------------
// K5: exclusive scan of cnt -> start, cur. Single block, 25 elems/thread.
// ---------------------------------------------------------------------------
__global__ __launch_bounds__(1024) void scan_kernel(
        const int* __restrict__ cnt, int* __restrict__ start,
        int* __restrict__ cur, int nb, int E) {
    __shared__ int tot[1024];
    int t = threadIdx.x;
    int v[25]; int sum = 0;
    #pragma unroll
    for (int j = 0; j < 25; ++j) {
        int i = t * 25 + j;
        v[j] = (i < nb) ? cnt[i] : 0;
        sum += v[j];
    }
    tot[t] = sum;
    __syncthreads();
    for (int d = 1; d < 1024; d <<= 1) {
        int val = tot[t];
        int add = (t >= d) ? tot[t - d] : 0;
        __syncthreads();
        tot[t] = val + add;
        __syncthreads();
    }
    int ex = (t == 0) ? 0 : tot[t - 1];
    #pragma unroll
    for (int j = 0; j < 25; ++j) {
        int i = t * 25 + j;
        if (i < nb) { start[i] = ex; cur[i] = ex; }
        ex += v[j];
    }
    if (t == 1023) start[nb] = ex;   // == E
}

// ---------------------------------------------------------------------------
// K6: block rank-and-reserve binning (single 100KB LDS array, in-place
// count -> base). pos[e], recs[pos] = src | dstl<<16 (dstl = 1 bit).
// ---------------------------------------------------------------------------
__global__ __launch_bounds__(1024) void binpos_kernel(
        const int* __restrict__ ei, int* __restrict__ cur,
        int* __restrict__ pos, uint_t* __restrict__ recs, int E) {
    __shared__ int lcnt[NB];
    int t = threadIdx.x;
    for (int i = t; i < NB; i += 1024) lcnt[i] = 0;
    __syncthreads();
    int base = blockIdx.x * 16384;
    int myrank[16], mybkt[16];
    #pragma unroll
    for (int j = 0; j < 16; ++j) {
        int e = base + t + j * 1024;
        if (e < E) {
            int b = ei[E + e] >> NB_SHIFT;
            mybkt[j] = b;
            myrank[j] = atomicAdd(&lcnt[b], 1);
        }
    }
    __syncthreads();
    // in-place: lcnt[i] becomes the block's base for bucket i
    for (int i = t; i < NB; i += 1024) {
        int c = lcnt[i];
        lcnt[i] = c ? atomicAdd(&cur[i], c) : 0;
    }
    __syncthreads();
    #pragma unroll
    for (int j = 0; j < 16; ++j) {
        int e = base + t + j * 1024;
        if (e < E) {
            int p = lcnt[mybkt[j]] + myrank[j];
            pos[e] = p;
            uint_t src  = (uint_t)ei[e];                 // < 65536
            uint_t dstl = (uint_t)(ei[E + e] & ((1 << NB_SHIFT) - 1));
            recs[p] = src | (dstl << 16);
        }
    }
}

// ---------------------------------------------------------------------------
// K8a: streaming edge GEMM from ea (f32, contiguous unsorted tiles):
// msgl[pos[e]] = bf16(ea[e] @ WemT16). Operand-swapped MFMA -> lane holds
// 4 consecutive channels of edge l15 -> 4 packed uint2 stores per tile.
// Straight-line fast path when all TPW tiles are in range.
// ---------------------------------------------------------------------------
__global__ __launch_bounds__(256) void msg_stream_kernel(
        const float* __restrict__ ea, const int* __restrict__ pos,
        const ushort_t* __restrict__ WemT16, ushort_t* __restrict__ msgl, int E) {
    int tid = threadIdx.x;
    int g = blockIdx.x * 4 + (tid >> 6);     // global wave id
    int grp = g >> 1;
    int chBase = (g & 1) << 6;
    int t0 = grp * (TPW * 16);
    if (t0 >= E) return;
    int lane = tid & 63, l15 = lane & 15, quad = lane >> 4;

    bf16x8 B[4][2];
    #pragma unroll
    for (int ct = 0; ct < 4; ++ct)
        #pragma unroll
        for (int kk = 0; kk < 2; ++kk)
            B[ct][kk] = __builtin_bit_cast(bf16x8, *((const uint4*)
                &WemT16[(size_t)(chBase + ct * 16 + l15) * 64 + kk * 32 + quad * 8]));

    if (t0 + TPW * 16 <= E) {
        // ---- fast path: all tiles valid; loads all issue up front ----
        bf16x8 a0[TPW], a1[TPW];
        int pr[TPW];
        #pragma unroll
        for (int tt = 0; tt < TPW; ++tt) {
            int t16 = t0 + tt * 16;
            const float* rowp = &ea[(size_t)(t16 + l15) * 64];
            const float4* sA = (const float4*)(rowp + quad * 8);
            float4 v0 = sA[0], v1 = sA[1];
            uint4 w0;
            w0.x = pack2(v0.x, v0.y);
            w0.y = pack2(v0.z, v0.w);
            w0.z = pack2(v1.x, v1.y);
            w0.w = pack2(v1.z, v1.w);
            a0[tt] = __builtin_bit_cast(bf16x8, w0);
            const float4* sB = (const float4*)(rowp + 32 + quad * 8);
            float4 v2 = sB[0], v3 = sB[1];
            uint4 w1;
            w1.x = pack2(v2.x, v2.y);
            w1.y = pack2(v2.z, v2.w);
            w1.z = pack2(v3.x, v3.y);
            w1.w = pack2(v3.z, v3.w);
            a1[tt] = __builtin_bit_cast(bf16x8, w1);
            pr[tt] = pos[t16 + l15];
        }
        #pragma unroll
        for (int tt = 0; tt < TPW; ++tt) {
            f32x4 acc[4] = {{0.f,0.f,0.f,0.f},{0.f,0.f,0.f,0.f},
                            {0.f,0.f,0.f,0.f},{0.f,0.f,0.f,0.f}};
            #pragma unroll
            for (int ct = 0; ct < 4; ++ct)   // SWAPPED operands
                acc[ct] = __builtin_amdgcn_mfma_f32_16x16x32_bf16(B[ct][0], a0[tt], acc[ct], 0, 0, 0);
            #pragma unroll
            for (int ct = 0; ct < 4; ++ct)
                acc[ct] = __builtin_amdgcn_mfma_f32_16x16x32_bf16(B[ct][1], a1[tt], acc[ct], 0, 0, 0);
            #pragma unroll
            for (int ct = 0; ct < 4; ++ct) {
                uint2 w;
                w.x = pack2(acc[ct][0], acc[ct][1]);
                w.y = pack2(acc[ct][2], acc[ct][3]);
                *((uint2*)&msgl[(size_t)pr[tt] * 128 + chBase + ct * 16 + quad * 4]) = w;
            }
        }
    } else {
        // ---- tail path (unused when E % (TPW*16) == 0) ----
        for (int tt = 0; tt < TPW; ++tt) {
            int t16 = t0 + tt * 16;
            if (t16 >= E) break;
            const float* rowp = &ea[(size_t)(t16 + l15) * 64];
            const float4* sA = (const float4*)(rowp + quad * 8);
            float4 v0 = sA[0], v1 = sA[1];
            uint4 w0;
            w0.x = pack2(v0.x, v0.y);
            w0.y = pack2(v0.z, v0.w);
            w0.z = pack2(v1.x, v1.y);
            w0.w = pack2(v1.z, v1.w);
            bf16x8 a0 = __builtin_bit_cast(bf16x8, w0);
            const float4* sB = (const float4*)(rowp + 32 + quad * 8);
            float4 v2 = sB[0], v3 = sB[1];
            uint4 w1;
            w1.x = pack2(v2.x, v2.y);
            w1.y = pack2(v2.z, v2.w);
            w1.z = pack2(v3.x, v3.y);
            w1.w = pack2(v3.z, v3.w);
            bf16x8 a1 = __builtin_bit_cast(bf16x8, w1);
            int pr = pos[t16 + l15];

            f32x4 acc[4] = {{0.f,0.f,0.f,0.f},{0.f,0.f,0.f,0.f},
                            {0.f,0.f,0.f,0.f},{0.f,0.f,0.f,0.f}};
            #pragma unroll
            for (int ct = 0; ct < 4; ++ct)
                acc[ct] = __builtin_amdgcn_mfma_f32_16x16x32_bf16(B[ct][0], a0, acc[ct], 0, 0, 0);
            #pragma unroll
            for (int ct = 0; ct < 4; ++ct)
                acc[ct] = __builtin_amdgcn_mfma_f32_16x16x32_bf16(B[ct][1], a1, acc[ct], 0, 0, 0);
            #pragma unroll
            for (int ct = 0; ct < 4; ++ct) {
                uint2 w;
                w.x = pack2(acc[ct][0], acc[ct][1]);
                w.y = pack2(acc[ct][2], acc[ct][3]);
                *((uint2*)&msgl[(size_t)pr * 128 + chBase + ct * 16 + quad * 4]) = w;
            }
        }
    }
}

// ---------------------------------------------------------------------------
// K8b: wave-per-bucket segment sum, register accumulators. 4 edges per
// iteration (quarter q owns edge p = s0+q+4k), uint4 (16B) row loads,
// 2-deep rec prefetch + 1-deep data pipeline. Full-wave shfl reduce.
// ---------------------------------------------------------------------------
__global__ __launch_bounds__(256) void segsum_kernel(
        const ushort_t* __restrict__ msgl, const ushort_t* __restrict__ ub,
        const uint_t* __restrict__ recs, const int* __restrict__ start,
        const float* __restrict__ beta, float* __restrict__ out, int N) {
    int wid = blockIdx.x * 4 + (threadIdx.x >> 6);   // bucket id
    if (wid >= NB) return;
    int lane = threadIdx.x & 63;
    int q = lane >> 4;             // edge slot within iteration (0..3)
    int c16 = lane & 15;           // channel group: ch 8*c16 .. 8*c16+7

    int s0 = start[wid], s1 = start[wid + 1];
    float a0[8] = {0.f,0.f,0.f,0.f,0.f,0.f,0.f,0.f};
    float a1[8] = {0.f,0.f,0.f,0.f,0.f,0.f,0.f,0.f};

    int pA = s0 + q;
    uint_t recA = (pA < s1) ? recs[pA] : 0u;
    int pB = pA + 4;
    uint_t recB = (pB < s1) ? recs[pB] : 0u;

    int pcA = (pA < s1) ? pA : 0;
    uint4 mvA = *(const uint4*)&msgl[(size_t)pcA * 128 + (c16 << 3)];
    uint4 uvA = *(const uint4*)&ub[(size_t)(recA & 0xFFFFu) * 128 + (c16 << 3)];

    while (pA < s1) {
        // prefetch rec two iterations ahead; issue next iteration's data
        int pC = pB + 4;
        uint_t recC = (pC < s1) ? recs[pC] : 0u;
        int pcB = (pB < s1) ? pB : pcA;
        uint4 mvB = *(const uint4*)&msgl[(size_t)pcB * 128 + (c16 << 3)];
        uint4 uvB = *(const uint4*)&ub[(size_t)(recB & 0xFFFFu) * 128 + (c16 << 3)];

        float w1 = (recA >> 16) ? 1.f : 0.f;
        float w0 = 1.f - w1;
        {
            float mlo, mhi;
            mlo = __uint_as_float(mvA.x << 16)         + __uint_as_float(uvA.x << 16);
            mhi = __uint_as_float(mvA.x & 0xFFFF0000u) + __uint_as_float(uvA.x & 0xFFFF0000u);
            mlo = fmaxf(mlo, 0.01f * mlo); mhi = fmaxf(mhi, 0.01f * mhi);
            a0[0] += mlo * w0; a1[0] += mlo * w1;
            a0[1] += mhi * w0; a1[1] += mhi * w1;
            mlo = __uint_as_float(mvA.y << 16)         + __uint_as_float(uvA.y << 16);
            mhi = __uint_as_float(mvA.y & 0xFFFF0000u) + __uint_as_float(uvA.y & 0xFFFF0000u);
            mlo = fmaxf(mlo, 0.01f * mlo); mhi = fmaxf(mhi, 0.01f * mhi);
            a0[2] += mlo * w0; a1[2] += mlo * w1;
            a0[3] += mhi * w0; a1[3] += mhi * w1;
            mlo = __uint_as_float(mvA.z << 16)         + __uint_as_float(uvA.z << 16);
            mhi = __uint_as_float(mvA.z & 0xFFFF0000u) + __uint_as_float(uvA.z & 0xFFFF0000u);
            mlo = fmaxf(mlo, 0.01f * mlo); mhi = fmaxf(mhi, 0.01f * mhi);
            a0[4] += mlo * w0; a1[4] += mlo * w1;
            a0[5] += mhi * w0; a1[5] += mhi * w1;
            mlo = __uint_as_float(mvA.w << 16)         + __uint_as_float(uvA.w << 16);
            mhi = __uint_as_float(mvA.w & 0xFFFF0000u) + __uint_as_float(uvA.w & 0xFFFF0000u);
            mlo = fmaxf(mlo, 0.01f * mlo); mhi = fmaxf(mhi, 0.01f * mhi);
            a0[6] += mlo * w0; a1[6] += mlo * w1;
            a0[7] += mhi * w0; a1[7] += mhi * w1;
        }

        pcA = pcB;
        pA = pB; recA = recB; mvA = mvB; uvA = uvB;
        pB = pC; recB = recC;
    }

    // reduce across the 4 quarters (all lanes end with full sums)
    #pragma unroll
    for (int j = 0; j < 8; ++j) {
        a0[j] += __shfl_xor(a0[j], 16);
        a0[j] += __shfl_xor(a0[j], 32);
        a1[j] += __shfl_xor(a1[j], 16);
        a1[j] += __shfl_xor(a1[j], 32);
    }

    float rb = beta[0];
    rb = rb > 0.f ? rb : 0.f;
    int h   = lane >> 5;           // node half
    int sub = (lane >> 4) & 1;     // which float4 of the 8-ch group
    int n = (wid << 1) + h;
    if (n < N) {
        float x0, x1, x2, x3;
        if (h == 0) {
            if (sub == 0) { x0 = a0[0]; x1 = a0[1]; x2 = a0[2]; x3 = a0[3]; }
            else          { x0 = a0[4]; x1 = a0[5]; x2 = a0[6]; x3 = a0[7]; }
        } else {
            if (sub == 0) { x0 = a1[0]; x1 = a1[1]; x2 = a1[2]; x3 = a1[3]; }
            else          { x0 = a1[4]; x1 = a1[5]; x2 = a1[6]; x3 = a1[7]; }
        }
        float4 v;
        v.x = rb / (1.f + __expf(-x0));
        v.y = rb / (1.f + __expf(-x1));
        v.z = rb / (1.f + __expf(-x2));
        v.w = rb / (1.f + __expf(-x3));
        ((float4*)out)[(size_t)n * 32 + c16 * 2 + sub] = v;
    }
}

// ---------------------------------------------------------------------------
extern "C" void kernel_launch(void* const* d_in, const int* in_sizes, int n_in,
                              void* d_out, int out_size, void* d_ws, size_t ws_size,
                              hipStream_t stream) {
    const float* x    = (const float*)d_in[0];
    const int*   ei   = (const int*)d_in[1];
    const float* ea   = (const float*)d_in[2];
    const float* Wx   = (const float*)d_in[3];
    const float* bx   = (const float*)d_in[4];
    const float* We   = (const float*)d_in[5];
    const float* be   = (const float*)d_in[6];
    const float* Wm   = (const float*)d_in[7];
    const float* bm   = (const float*)d_in[8];
    const float* beta = (const float*)d_in[9];

    int N = in_sizes[0] / 128;   // 50000
    int E = in_sizes[2] / 64;    // 600000

    float* out = (float*)d_out;

    // workspace layout (bytes)
    char* ws = (char*)d_ws;
    ushort_t* WxmT16 = (ushort_t*)(ws);                    // 32768
    ushort_t* WemT16 = (ushort_t*)(ws + 32768);            // 16384
    float*    bf     = (float*)(ws + 49152);               // 512
    ushort_t* ub     = (ushort_t*)(ws + 65536);            // 12.8 MB (bf16)
    size_t off = 65536 + (size_t)N * 128 * 2;
    uint_t* recs   = (uint_t*)(ws + off);                  // 2.4 MB
    off += (size_t)E * 4;
    int* pos       = (int*)(ws + off);                     // 2.4 MB
    off += (size_t)E * 4;
    int* cnt       = (int*)(ws + off);                     // 100 KB
    int* startb    = (int*)(ws + off + 131072);            // 100 KB + 4
    int* cur       = (int*)(ws + off + 262144);            // 100 KB
    ushort_t* msgl = (ushort_t*)(ws + off + 393216);       // 153.6 MB (bf16)

    hipMemsetAsync(cnt, 0, (size_t)NB * sizeof(int), stream);

    fuse_weights_kernel<<<(24704 + 255) / 256, 256, 0, stream>>>(
        Wx, bx, We, be, Wm, bm, WxmT16, WemT16, bf);

    node_gemm_kernel<<<(N / 16 * 2 + 3) / 4, 256, 0, stream>>>(
        x, WxmT16, bf, ub, N);

    int nbBlocks = (E + 16383) / 16384;   // 37
    hist_kernel<<<nbBlocks, 1024, 0, stream>>>(ei, cnt, E);
    scan_kernel<<<1, 1024, 0, stream>>>(cnt, startb, cur, NB, E);
    binpos_kernel<<<nbBlocks, 1024, 0, stream>>>(ei, cur, pos, recs, E);

    int ntile  = (E + 15) / 16;                    // 37500
    int ngrp   = (ntile + TPW - 1) / TPW;          // 9375
    int nwaves = ngrp * 2;                         // 18750
    msg_stream_kernel<<<(nwaves + 3) / 4, 256, 0, stream>>>(
        ea, pos, WemT16, msgl, E);

    segsum_kernel<<<(NB + 3) / 4, 256, 0, stream>>>(
        msgl, ub, recs, startb, beta, out, N);
}